// Round 1
// baseline (370.357 us; speedup 1.0000x reference)
//
#include <hip/hip_runtime.h>
#include <cstddef>

// Problem constants: B=32, N=4096, D=256, K=8 slots, S=16, H=128, 3 iters.

__device__ __forceinline__ float sigmoid_f(float x){ return 1.f/(1.f+__expf(-x)); }
__device__ __forceinline__ float tanh_f(float x){ return 1.f - 2.f/(__expf(2.f*x)+1.f); }

// ---------------- K0: prep (weights, init slots, q1, zero accumulators) ----
__global__ __launch_bounds__(256) void k_prep(
    const float* __restrict__ lnw, const float* __restrict__ lnb,
    const float* __restrict__ wk, const float* __restrict__ wv,
    const float* __restrict__ init_slots,
    const float* __restrict__ ln_s_w, const float* __restrict__ ln_s_b,
    const float* __restrict__ wq,
    float* __restrict__ wprep, float* __restrict__ mt,
    float* __restrict__ qbuf, float* __restrict__ upd, float* __restrict__ Abuf,
    float* __restrict__ slots_out)
{
  int t = threadIdx.x;
  // Combined LN-scaled projection weights: rows 0..15 = lnw*wk, 16..31 = lnw*wv
  for (int i = t; i < 8192; i += 256) {
    int s = i >> 8, d = i & 255;
    float w = (s < 16) ? wk[s*256+d] : wv[(s-16)*256+d];
    wprep[i] = lnw[d]*w;
  }
  // m[s] = sum_d lnw*w ; t[s] = sum_d lnb*w   (32 s-values x 8 lanes each)
  {
    int s = t >> 3, j = t & 7;
    float m = 0.f, tv = 0.f;
    for (int d = j; d < 256; d += 8) {
      float w = (s < 16) ? wk[s*256+d] : wv[(s-16)*256+d];
      m  = fmaf(lnw[d], w, m);
      tv = fmaf(lnb[d], w, tv);
    }
    m += __shfl_xor(m,1);  m += __shfl_xor(m,2);  m += __shfl_xor(m,4);
    tv += __shfl_xor(tv,1); tv += __shfl_xor(tv,2); tv += __shfl_xor(tv,4);
    if (j == 0) { mt[s] = m; mt[32+s] = tv; }
  }
  // init slots into d_out, zero accumulators (ws is poisoned before each launch)
  #pragma unroll
  for (int j2 = 0; j2 < 16; ++j2) {
    slots_out[t*16+j2] = init_slots[t*16+j2];
    upd[t*16+j2] = 0.f;
  }
  Abuf[t] = 0.f;
  // q for iteration 1: thread t = (b,k) row
  float sl[16];
  #pragma unroll
  for (int j2 = 0; j2 < 16; ++j2) sl[j2] = init_slots[t*16+j2];
  float mu = 0.f;
  #pragma unroll
  for (int j2 = 0; j2 < 16; ++j2) mu += sl[j2];
  mu *= (1.f/16.f);
  float var = 0.f;
  #pragma unroll
  for (int j2 = 0; j2 < 16; ++j2) { float d = sl[j2]-mu; var = fmaf(d,d,var); }
  var *= (1.f/16.f);
  float rstd = rsqrtf(var + 1e-5f);
  float y[16];
  #pragma unroll
  for (int j2 = 0; j2 < 16; ++j2) y[j2] = (sl[j2]-mu)*rstd*ln_s_w[j2] + ln_s_b[j2];
  #pragma unroll
  for (int tq = 0; tq < 16; ++tq) {
    float q = 0.f;
    #pragma unroll
    for (int s2 = 0; s2 < 16; ++s2) q = fmaf(y[s2], wq[tq*16+s2], q);
    qbuf[t*16+tq] = q;
  }
}

// ---------------- K1: fused LayerNorm + K/V projection ----------------
// One thread per (b,n) row; 32 fp32 accumulators; LN folded in algebraically:
// out[s] = rstd*(dot(x, W'[s]) - mu*m[s]) + t[s],  W' = lnw .* w
__global__ __launch_bounds__(256) void k_proj(
    const float* __restrict__ x, const float* __restrict__ wprep,
    const float* __restrict__ mt,
    float* __restrict__ kout, float* __restrict__ vout)
{
  int row = blockIdx.x*256 + threadIdx.x;
  const float* xr = x + (size_t)row*256;
  float acc[32];
  #pragma unroll
  for (int s = 0; s < 32; ++s) acc[s] = 0.f;
  float sum = 0.f, sumsq = 0.f;
  float4 nx0 = *(const float4*)(xr+0);
  float4 nx1 = *(const float4*)(xr+4);
  float4 nx2 = *(const float4*)(xr+8);
  float4 nx3 = *(const float4*)(xr+12);
  for (int dc = 0; dc < 16; ++dc) {
    float4 x0 = nx0, x1 = nx1, x2 = nx2, x3 = nx3;
    if (dc < 15) {  // prefetch next 64B chunk of this row
      const float* xn = xr + (dc+1)*16;
      nx0 = *(const float4*)(xn+0);
      nx1 = *(const float4*)(xn+4);
      nx2 = *(const float4*)(xn+8);
      nx3 = *(const float4*)(xn+12);
    }
    float xe[16] = {x0.x,x0.y,x0.z,x0.w, x1.x,x1.y,x1.z,x1.w,
                    x2.x,x2.y,x2.z,x2.w, x3.x,x3.y,x3.z,x3.w};
    #pragma unroll
    for (int j = 0; j < 16; ++j) { sum += xe[j]; sumsq = fmaf(xe[j], xe[j], sumsq); }
    const float* wp = wprep + dc*16;  // uniform address -> scalar loads
    #pragma unroll
    for (int s = 0; s < 32; ++s) {
      const float* w = wp + s*256;
      #pragma unroll
      for (int j = 0; j < 16; ++j) acc[s] = fmaf(xe[j], w[j], acc[s]);
    }
  }
  float mu = sum*(1.f/256.f);
  float var = sumsq*(1.f/256.f) - mu*mu;
  float rstd = rsqrtf(var + 1e-5f);
  float o[32];
  #pragma unroll
  for (int s = 0; s < 32; ++s) o[s] = fmaf(rstd, acc[s] - mu*mt[s], mt[32+s]);
  float4* ko = (float4*)(kout + (size_t)row*16);
  ko[0] = make_float4(o[0],o[1],o[2],o[3]);
  ko[1] = make_float4(o[4],o[5],o[6],o[7]);
  ko[2] = make_float4(o[8],o[9],o[10],o[11]);
  ko[3] = make_float4(o[12],o[13],o[14],o[15]);
  float4* vo = (float4*)(vout + (size_t)row*16);
  vo[0] = make_float4(o[16],o[17],o[18],o[19]);
  vo[1] = make_float4(o[20],o[21],o[22],o[23]);
  vo[2] = make_float4(o[24],o[25],o[26],o[27]);
  vo[3] = make_float4(o[28],o[29],o[30],o[31]);
}

// ---------------- K2: logits + softmax-over-slots + update accumulation ----
// Block = (b, chunk of 256 n). Phase 1: per-n softmax over 8 slots -> p tile
// in LDS (+EPS). Phase 2: threads = (kk,s,half) accumulate sum_n p*v and
// sum_n p, atomically added to global accumulators (normalized later).
__global__ __launch_bounds__(256) void k_attn(
    const float* __restrict__ kproj, const float* __restrict__ vproj,
    const float* __restrict__ qbuf,
    float* __restrict__ upd, float* __restrict__ Abuf,
    float* __restrict__ attn_out, int write_attn)
{
  __shared__ float qs[128];
  __shared__ float ptile[8*257];  // stride 257: 2-way max bank aliasing (free)
  int b = blockIdx.x >> 4;
  int n0 = (blockIdx.x & 15) * 256;
  int t = threadIdx.x;
  if (t < 128) qs[t] = qbuf[b*128 + t];
  __syncthreads();
  {
    const float* kr = kproj + ((size_t)(b*4096 + n0 + t))*16;
    float kv[16];
    #pragma unroll
    for (int j = 0; j < 16; j += 4) {
      float4 f = *(const float4*)(kr+j);
      kv[j]=f.x; kv[j+1]=f.y; kv[j+2]=f.z; kv[j+3]=f.w;
    }
    float lg[8];
    #pragma unroll
    for (int kk = 0; kk < 8; ++kk) {
      float a = 0.f;
      #pragma unroll
      for (int s = 0; s < 16; ++s) a = fmaf(qs[kk*16+s], kv[s], a);
      lg[kk] = a*0.25f;  // scale = 16^-0.5
    }
    float mx = lg[0];
    #pragma unroll
    for (int kk = 1; kk < 8; ++kk) mx = fmaxf(mx, lg[kk]);
    float se = 0.f;
    #pragma unroll
    for (int kk = 0; kk < 8; ++kk) { lg[kk] = __expf(lg[kk]-mx); se += lg[kk]; }
    float inv = 1.f/se;
    #pragma unroll
    for (int kk = 0; kk < 8; ++kk) {
      float p = fmaf(lg[kk], inv, 1e-8f);   // softmax + EPS (pre-renorm)
      ptile[kk*257 + t] = p;
      if (write_attn) attn_out[((size_t)(b*8+kk))*4096 + n0 + t] = p;
    }
  }
  __syncthreads();
  {
    int kk = t >> 5, r = t & 31, s = r >> 1, half = r & 1;
    const float* pr = ptile + kk*257 + half*128;
    const float* vr = vproj + ((size_t)(b*4096 + n0 + half*128))*16 + s;
    float acc = 0.f, asum = 0.f;
    #pragma unroll 8
    for (int i = 0; i < 128; ++i) {
      float p = pr[i];
      asum += p;
      acc = fmaf(p, vr[i*16], acc);
    }
    acc  += __shfl_xor(acc, 1);
    asum += __shfl_xor(asum, 1);
    if (half == 0) {
      atomicAdd(upd + (b*8+kk)*16 + s, acc);
      if (s == 0) atomicAdd(Abuf + b*8 + kk, asum);
    }
  }
}

// ---------------- K3: GRU cell + LN + MLP + slots update + next-iter q -----
// 16 blocks x 256 threads; thread = (b,k,s); 16-lane group per (b,k).
__global__ __launch_bounds__(256) void k_gru(
    float* __restrict__ upd, float* __restrict__ Abuf,
    float* __restrict__ slots, float* __restrict__ qbuf,
    const float* __restrict__ w_ih, const float* __restrict__ w_hh,
    const float* __restrict__ b_ih, const float* __restrict__ b_hh,
    const float* __restrict__ mlp_w1, const float* __restrict__ mlp_b1,
    const float* __restrict__ mlp_w2, const float* __restrict__ mlp_b2,
    const float* __restrict__ ln_m_w, const float* __restrict__ ln_m_b,
    const float* __restrict__ ln_s_w, const float* __restrict__ ln_s_b,
    const float* __restrict__ wq, int prep_next)
{
  __shared__ float s_wih[48*17], s_whh[48*17];   // stride 17: conflict-free
  __shared__ float s_bih[48], s_bhh[48];
  __shared__ float s_w1[128*17], s_b1[128];
  __shared__ float s_w2[16*129], s_b2[16];       // stride 129: conflict-free
  __shared__ float s_lnmw[16], s_lnmb[16], s_lnsw[16], s_lnsb[16];
  __shared__ float s_wq[16*17];
  int t = threadIdx.x;
  for (int i = t; i < 768; i += 256) {
    int g = i >> 4, j = i & 15;
    s_wih[g*17+j] = w_ih[i];
    s_whh[g*17+j] = w_hh[i];
  }
  for (int i = t; i < 2048; i += 256) {
    int r = i >> 4, c = i & 15;
    s_w1[r*17+c] = mlp_w1[i];
    int r2 = i >> 7, c2 = i & 127;
    s_w2[r2*129+c2] = mlp_w2[i];
  }
  if (t < 48) { s_bih[t] = b_ih[t]; s_bhh[t] = b_hh[t]; }
  if (t < 128) s_b1[t] = mlp_b1[t];
  if (t < 16) {
    s_b2[t] = mlp_b2[t];
    s_lnmw[t] = ln_m_w[t]; s_lnmb[t] = ln_m_b[t];
    s_lnsw[t] = ln_s_w[t]; s_lnsb[t] = ln_s_b[t];
  }
  for (int i = t; i < 256; i += 256) {
    int r = i >> 4, c = i & 15;
    s_wq[r*17+c] = wq[i];
  }
  __syncthreads();

  int bk = blockIdx.x*16 + (t >> 4);
  int s = t & 15;
  int laneBase = (t & 63) & ~15;   // 16-lane group lives inside one wave

  float inv = 1.f / Abuf[bk];
  float u[16], h[16];
  #pragma unroll
  for (int j = 0; j < 16; ++j) {
    u[j] = upd[bk*16+j] * inv;     // normalized updates
    h[j] = slots[bk*16+j];         // slots_prev
  }
  float hs = slots[bk*16+s];       // avoid dynamic reg-array index

  float gir = s_bih[s],  giz = s_bih[16+s], gin = s_bih[32+s];
  float ghr = s_bhh[s],  ghz = s_bhh[16+s], ghn = s_bhh[32+s];
  #pragma unroll
  for (int j = 0; j < 16; ++j) {
    gir = fmaf(u[j], s_wih[s*17+j], gir);
    giz = fmaf(u[j], s_wih[(16+s)*17+j], giz);
    gin = fmaf(u[j], s_wih[(32+s)*17+j], gin);
    ghr = fmaf(h[j], s_whh[s*17+j], ghr);
    ghz = fmaf(h[j], s_whh[(16+s)*17+j], ghz);
    ghn = fmaf(h[j], s_whh[(32+s)*17+j], ghn);
  }
  float rr = sigmoid_f(gir + ghr);
  float zz = sigmoid_f(giz + ghz);
  float nn = tanh_f(gin + rr*ghn);
  float hn = (1.f-zz)*nn + zz*hs;

  // LayerNorm(h) over the 16-lane group
  float ssum = hn;
  #pragma unroll
  for (int m = 1; m < 16; m <<= 1) ssum += __shfl_xor(ssum, m);
  float mu = ssum*(1.f/16.f);
  float dv = hn - mu;
  float vs = dv*dv;
  #pragma unroll
  for (int m = 1; m < 16; m <<= 1) vs += __shfl_xor(vs, m);
  float rstd = rsqrtf(vs*(1.f/16.f) + 1e-5f);
  float y = dv*rstd*s_lnmw[s] + s_lnmb[s];

  float yv[16];
  #pragma unroll
  for (int j = 0; j < 16; ++j) yv[j] = __shfl(y, laneBase + j);

  // MLP layer 1: thread s owns hidden units j = i*16+s (bank-friendly)
  float h1[8];
  #pragma unroll
  for (int i = 0; i < 8; ++i) {
    int jj = i*16 + s;
    float a = s_b1[jj];
    #pragma unroll
    for (int q = 0; q < 16; ++q) a = fmaf(yv[q], s_w1[jj*17+q], a);
    h1[i] = fmaxf(a, 0.f);
  }
  // MLP layer 2 via shuffles
  float o = s_b2[s];
  #pragma unroll
  for (int i = 0; i < 8; ++i) {
    #pragma unroll
    for (int sp = 0; sp < 16; ++sp) {
      float hv = __shfl(h1[i], laneBase + sp);
      o = fmaf(hv, s_w2[s*129 + i*16 + sp], o);
    }
  }
  float slot_new = hn + o;
  slots[bk*16+s] = slot_new;

  if (prep_next) {
    // q for next iteration: wq @ LN_s(slots_new)
    float ss = slot_new;
    #pragma unroll
    for (int m = 1; m < 16; m <<= 1) ss += __shfl_xor(ss, m);
    float mu2 = ss*(1.f/16.f);
    float d2 = slot_new - mu2;
    float v2 = d2*d2;
    #pragma unroll
    for (int m = 1; m < 16; m <<= 1) v2 += __shfl_xor(v2, m);
    float rstd2 = rsqrtf(v2*(1.f/16.f) + 1e-5f);
    float y2 = d2*rstd2*s_lnsw[s] + s_lnsb[s];
    float qv = 0.f;
    #pragma unroll
    for (int sp = 0; sp < 16; ++sp) qv = fmaf(__shfl(y2, laneBase+sp), s_wq[s*17+sp], qv);
    qbuf[bk*16+s] = qv;
    // zero accumulators for next iteration (reads above are same-wave lockstep)
    upd[bk*16+s] = 0.f;
    if (s == 0) Abuf[bk] = 0.f;
  }
}

// ---------------- K4: normalize attn rows by A[b,k] ----------------
__global__ __launch_bounds__(256) void k_scale(float* __restrict__ attn,
                                               const float* __restrict__ Abuf)
{
  int bk = blockIdx.x;
  float inv = 1.f / Abuf[bk];
  float4* p = (float4*)(attn + (size_t)bk*4096);
  #pragma unroll 4
  for (int i = threadIdx.x; i < 1024; i += 256) {
    float4 v = p[i];
    v.x *= inv; v.y *= inv; v.z *= inv; v.w *= inv;
    p[i] = v;
  }
}

extern "C" void kernel_launch(void* const* d_in, const int* in_sizes, int n_in,
                              void* d_out, int out_size, void* d_ws, size_t ws_size,
                              hipStream_t stream)
{
  const float* inputs     = (const float*)d_in[0];
  const float* init_slots = (const float*)d_in[1];
  const float* ln_in_w    = (const float*)d_in[2];
  const float* ln_in_b    = (const float*)d_in[3];
  const float* ln_s_w     = (const float*)d_in[4];
  const float* ln_s_b     = (const float*)d_in[5];
  const float* ln_m_w     = (const float*)d_in[6];
  const float* ln_m_b     = (const float*)d_in[7];
  const float* wq         = (const float*)d_in[8];
  const float* wk         = (const float*)d_in[9];
  const float* wv         = (const float*)d_in[10];
  const float* w_ih       = (const float*)d_in[11];
  const float* w_hh       = (const float*)d_in[12];
  const float* b_ih       = (const float*)d_in[13];
  const float* b_hh       = (const float*)d_in[14];
  const float* mlp_w1     = (const float*)d_in[15];
  const float* mlp_b1     = (const float*)d_in[16];
  const float* mlp_w2     = (const float*)d_in[17];
  const float* mlp_b2     = (const float*)d_in[18];

  // workspace layout (floats); total ~16.1 MiB
  float* ws    = (float*)d_ws;
  float* wprep = ws;                 // 8192
  float* mt    = ws + 8192;          // 64 (m[32], t[32])
  float* qbuf  = ws + 8320;          // 4096
  float* upd   = ws + 12416;         // 4096
  float* Abuf  = ws + 16512;         // 256
  float* kproj = ws + 16768;         // 2097152
  float* vproj = kproj + 2097152;    // 2097152

  float* out   = (float*)d_out;
  float* slots = out;                // [32,8,16]
  float* attn  = out + 4096;         // [32,8,4096]

  k_prep<<<1, 256, 0, stream>>>(ln_in_w, ln_in_b, wk, wv, init_slots,
                                ln_s_w, ln_s_b, wq,
                                wprep, mt, qbuf, upd, Abuf, slots);
  k_proj<<<512, 256, 0, stream>>>(inputs, wprep, mt, kproj, vproj);
  for (int it = 0; it < 3; ++it) {
    int last = (it == 2);
    k_attn<<<512, 256, 0, stream>>>(kproj, vproj, qbuf, upd, Abuf, attn, last);
    k_gru<<<16, 256, 0, stream>>>(upd, Abuf, slots, qbuf,
                                  w_ih, w_hh, b_ih, b_hh,
                                  mlp_w1, mlp_b1, mlp_w2, mlp_b2,
                                  ln_m_w, ln_m_b, ln_s_w, ln_s_b,
                                  wq, last ? 0 : 1);
  }
  k_scale<<<256, 256, 0, stream>>>(attn, Abuf);
}

// Round 2
// 320.210 us; speedup vs baseline: 1.1566x; 1.1566x over previous
//
#include <hip/hip_runtime.h>
#include <cstddef>

// Problem constants: B=32, N=4096, D=256, K=8 slots, S=16, H=128, 3 iters.

__device__ __forceinline__ float sigmoid_f(float x){ return 1.f/(1.f+__expf(-x)); }
__device__ __forceinline__ float tanh_f(float x){ return 1.f - 2.f/(__expf(2.f*x)+1.f); }

// ---------------- K0: prep (weights, init slots, q1, zero accumulators) ----
// Grid = 32 blocks. All blocks stripe wprepT; block 0 also does the small stuff.
// wprepT layout: [(p*4 + c)*32 + s][16 j], weight for (s, d=p*64+c*16+j), LN-scaled.
__global__ __launch_bounds__(256) void k_prep(
    const float* __restrict__ lnw, const float* __restrict__ lnb,
    const float* __restrict__ wk, const float* __restrict__ wv,
    const float* __restrict__ init_slots,
    const float* __restrict__ ln_s_w, const float* __restrict__ ln_s_b,
    const float* __restrict__ wq,
    float* __restrict__ wprepT, float* __restrict__ mt,
    float* __restrict__ qbuf, float* __restrict__ upd, float* __restrict__ Abuf,
    float* __restrict__ slots_out)
{
  int t = threadIdx.x;
  int i = blockIdx.x*256 + t;          // 32*256 == 8192 exactly
  {
    int j = i & 15, s = (i >> 4) & 31, c = (i >> 9) & 3, p = i >> 11;
    int d = p*64 + c*16 + j;
    float w = (s < 16) ? wk[s*256+d] : wv[(s-16)*256+d];
    wprepT[i] = lnw[d]*w;
  }
  if (blockIdx.x != 0) return;
  // m[s] = sum_d lnw*w ; t[s] = sum_d lnb*w   (32 s-values x 8 lanes each)
  {
    int s = t >> 3, j = t & 7;
    float m = 0.f, tv = 0.f;
    for (int d = j; d < 256; d += 8) {
      float w = (s < 16) ? wk[s*256+d] : wv[(s-16)*256+d];
      m  = fmaf(lnw[d], w, m);
      tv = fmaf(lnb[d], w, tv);
    }
    m += __shfl_xor(m,1);  m += __shfl_xor(m,2);  m += __shfl_xor(m,4);
    tv += __shfl_xor(tv,1); tv += __shfl_xor(tv,2); tv += __shfl_xor(tv,4);
    if (j == 0) { mt[s] = m; mt[32+s] = tv; }
  }
  // init slots into d_out, zero accumulators (ws is poisoned before each launch)
  #pragma unroll
  for (int j2 = 0; j2 < 16; ++j2) {
    slots_out[t*16+j2] = init_slots[t*16+j2];
    upd[t*16+j2] = 0.f;
  }
  Abuf[t] = 0.f;
  // q for iteration 1: thread t = (b,k) row
  float sl[16];
  #pragma unroll
  for (int j2 = 0; j2 < 16; ++j2) sl[j2] = init_slots[t*16+j2];
  float mu = 0.f;
  #pragma unroll
  for (int j2 = 0; j2 < 16; ++j2) mu += sl[j2];
  mu *= (1.f/16.f);
  float var = 0.f;
  #pragma unroll
  for (int j2 = 0; j2 < 16; ++j2) { float d = sl[j2]-mu; var = fmaf(d,d,var); }
  var *= (1.f/16.f);
  float rstd = rsqrtf(var + 1e-5f);
  float y[16];
  #pragma unroll
  for (int j2 = 0; j2 < 16; ++j2) y[j2] = (sl[j2]-mu)*rstd*ln_s_w[j2] + ln_s_b[j2];
  #pragma unroll
  for (int tq = 0; tq < 16; ++tq) {
    float q = 0.f;
    #pragma unroll
    for (int s2 = 0; s2 < 16; ++s2) q = fmaf(y[s2], wq[tq*16+s2], q);
    qbuf[t*16+tq] = q;
  }
}

// ---------------- K1: fused LayerNorm + K/V projection ----------------
// Block = 256 threads = 4 waves, handles 64 rows. Wave p owns columns
// [p*64, p*64+64) of all 64 rows (lane = row). Weight reads are wave-uniform
// (p forced to SGPR via readfirstlane) -> scalar loads of the chunk-contiguous
// wprepT. Partials (32 accs + sum + sumsq) combined across waves via LDS.
// LN folded in: out[s] = rstd*(dot - mu*m[s]) + t[s].
__global__ __launch_bounds__(256) void k_proj(
    const float* __restrict__ x, const float* __restrict__ wprepT,
    const float* __restrict__ mt,
    float* __restrict__ kout, float* __restrict__ vout)
{
  __shared__ float pbuf[4][64][35];   // stride 35: gcd(35,32)=1 -> <=2-way
  int t = threadIdx.x;
  int lane = t & 63;
  int p = __builtin_amdgcn_readfirstlane(t >> 6);
  int row = blockIdx.x*64 + lane;
  const float* xr = x + (size_t)row*256 + p*64;
  const float* wp = wprepT + p*2048;   // this wave's 4 chunks x 32 s x 16 j

  float acc[32];
  #pragma unroll
  for (int s = 0; s < 32; ++s) acc[s] = 0.f;
  float sum = 0.f, sumsq = 0.f;

  float4 n0 = *(const float4*)(xr+0);
  float4 n1 = *(const float4*)(xr+4);
  float4 n2 = *(const float4*)(xr+8);
  float4 n3 = *(const float4*)(xr+12);
  #pragma unroll 1
  for (int c = 0; c < 4; ++c) {
    float4 x0 = n0, x1 = n1, x2 = n2, x3 = n3;
    if (c < 3) {
      const float* xn = xr + (c+1)*16;
      n0 = *(const float4*)(xn+0);
      n1 = *(const float4*)(xn+4);
      n2 = *(const float4*)(xn+8);
      n3 = *(const float4*)(xn+12);
    }
    float xe[16] = {x0.x,x0.y,x0.z,x0.w, x1.x,x1.y,x1.z,x1.w,
                    x2.x,x2.y,x2.z,x2.w, x3.x,x3.y,x3.z,x3.w};
    #pragma unroll
    for (int j = 0; j < 16; ++j) { sum += xe[j]; sumsq = fmaf(xe[j], xe[j], sumsq); }
    const float* wc = wp + c*512;     // uniform -> s_load
    #pragma unroll
    for (int s = 0; s < 32; ++s) {
      const float* w = wc + s*16;
      #pragma unroll
      for (int j = 0; j < 16; ++j) acc[s] = fmaf(xe[j], w[j], acc[s]);
    }
  }
  #pragma unroll
  for (int s = 0; s < 32; ++s) pbuf[p][lane][s] = acc[s];
  pbuf[p][lane][32] = sum;
  pbuf[p][lane][33] = sumsq;
  __syncthreads();

  // Reduce: group g (wave) handles outputs s = g*8..g*8+7 for all 64 rows.
  int g = t >> 6, r = t & 63;
  float ts = 0.f, tq = 0.f;
  #pragma unroll
  for (int pp = 0; pp < 4; ++pp) { ts += pbuf[pp][r][32]; tq += pbuf[pp][r][33]; }
  float mu = ts*(1.f/256.f);
  float var = tq*(1.f/256.f) - mu*mu;
  float rstd = rsqrtf(var + 1e-5f);
  float o[8];
  #pragma unroll
  for (int j = 0; j < 8; ++j) {
    int a = g*8 + j;
    float v = 0.f;
    #pragma unroll
    for (int pp = 0; pp < 4; ++pp) v += pbuf[pp][r][a];
    o[j] = fmaf(rstd, v - mu*mt[a], mt[32+a]);
  }
  float* dst = ((g < 2) ? kout : vout) + (size_t)(blockIdx.x*64 + r)*16 + (g & 1)*8;
  *(float4*)(dst+0) = make_float4(o[0],o[1],o[2],o[3]);
  *(float4*)(dst+4) = make_float4(o[4],o[5],o[6],o[7]);
}

// ---------------- K2: logits + softmax-over-slots + update accumulation ----
// Block = (b, chunk of 256 n). Phase 1: stage v transposed into LDS, per-n
// softmax over 8 slots -> p tile in LDS (+EPS). Phase 2: threads = (kk,s,half)
// accumulate sum_n p*v and sum_n p from LDS, atomicAdd into global accums.
__global__ __launch_bounds__(256) void k_attn(
    const float* __restrict__ kproj, const float* __restrict__ vproj,
    const float* __restrict__ qbuf,
    float* __restrict__ upd, float* __restrict__ Abuf,
    float* __restrict__ attn_out, int write_attn)
{
  __shared__ float qs[128];
  __shared__ float ptile[8*257];    // stride 257: <=2-way aliasing (free)
  __shared__ float vtile[16*257];   // [s][n_local], stride 257
  int b = blockIdx.x >> 4;
  int n0 = (blockIdx.x & 15) * 256;
  int t = threadIdx.x;
  if (t < 128) qs[t] = qbuf[b*128 + t];

  float kv[16];
  {
    const float* kr = kproj + ((size_t)(b*4096 + n0 + t))*16;
    const float* vr = vproj + ((size_t)(b*4096 + n0 + t))*16;
    #pragma unroll
    for (int j = 0; j < 16; j += 4) {
      float4 f = *(const float4*)(kr+j);
      kv[j]=f.x; kv[j+1]=f.y; kv[j+2]=f.z; kv[j+3]=f.w;
      float4 g = *(const float4*)(vr+j);
      vtile[(j+0)*257+t]=g.x; vtile[(j+1)*257+t]=g.y;
      vtile[(j+2)*257+t]=g.z; vtile[(j+3)*257+t]=g.w;
    }
  }
  __syncthreads();   // qs + vtile ready
  {
    float lg[8];
    #pragma unroll
    for (int kk = 0; kk < 8; ++kk) {
      float a = 0.f;
      #pragma unroll
      for (int s = 0; s < 16; ++s) a = fmaf(qs[kk*16+s], kv[s], a);
      lg[kk] = a*0.25f;  // scale = 16^-0.5
    }
    float mx = lg[0];
    #pragma unroll
    for (int kk = 1; kk < 8; ++kk) mx = fmaxf(mx, lg[kk]);
    float se = 0.f;
    #pragma unroll
    for (int kk = 0; kk < 8; ++kk) { lg[kk] = __expf(lg[kk]-mx); se += lg[kk]; }
    float inv = 1.f/se;
    #pragma unroll
    for (int kk = 0; kk < 8; ++kk) {
      float pv = fmaf(lg[kk], inv, 1e-8f);   // softmax + EPS (pre-renorm)
      ptile[kk*257 + t] = pv;
      if (write_attn) attn_out[((size_t)(b*8+kk))*4096 + n0 + t] = pv;
    }
  }
  __syncthreads();   // ptile ready
  {
    int kk = t >> 5, r = t & 31, s = r >> 1, half = r & 1;
    const float* pr = ptile + kk*257 + half*128;
    const float* vr = vtile + s*257 + half*128;
    float acc = 0.f, asum = 0.f;
    #pragma unroll 8
    for (int i = 0; i < 128; ++i) {
      float pv = pr[i];
      asum += pv;
      acc = fmaf(pv, vr[i], acc);
    }
    acc  += __shfl_xor(acc, 1);
    asum += __shfl_xor(asum, 1);
    if (half == 0) {
      atomicAdd(upd + (b*8+kk)*16 + s, acc);
      if (s == 0) atomicAdd(Abuf + b*8 + kk, asum);
    }
  }
}

// ---------------- K3: GRU cell + LN + MLP + slots update + next-iter q -----
// 16 blocks x 256 threads; thread = (b,k,s); 16-lane group per (b,k).
__global__ __launch_bounds__(256) void k_gru(
    float* __restrict__ upd, float* __restrict__ Abuf,
    float* __restrict__ slots, float* __restrict__ qbuf,
    const float* __restrict__ w_ih, const float* __restrict__ w_hh,
    const float* __restrict__ b_ih, const float* __restrict__ b_hh,
    const float* __restrict__ mlp_w1, const float* __restrict__ mlp_b1,
    const float* __restrict__ mlp_w2, const float* __restrict__ mlp_b2,
    const float* __restrict__ ln_m_w, const float* __restrict__ ln_m_b,
    const float* __restrict__ ln_s_w, const float* __restrict__ ln_s_b,
    const float* __restrict__ wq, int prep_next)
{
  __shared__ float s_wih[48*17], s_whh[48*17];   // stride 17: conflict-free
  __shared__ float s_bih[48], s_bhh[48];
  __shared__ float s_w1[128*17], s_b1[128];
  __shared__ float s_w2[16*129], s_b2[16];       // stride 129: conflict-free
  __shared__ float s_lnmw[16], s_lnmb[16], s_lnsw[16], s_lnsb[16];
  __shared__ float s_wq[16*17];
  int t = threadIdx.x;
  for (int i = t; i < 768; i += 256) {
    int g = i >> 4, j = i & 15;
    s_wih[g*17+j] = w_ih[i];
    s_whh[g*17+j] = w_hh[i];
  }
  for (int i = t; i < 2048; i += 256) {
    int r = i >> 4, c = i & 15;
    s_w1[r*17+c] = mlp_w1[i];
    int r2 = i >> 7, c2 = i & 127;
    s_w2[r2*129+c2] = mlp_w2[i];
  }
  if (t < 48) { s_bih[t] = b_ih[t]; s_bhh[t] = b_hh[t]; }
  if (t < 128) s_b1[t] = mlp_b1[t];
  if (t < 16) {
    s_b2[t] = mlp_b2[t];
    s_lnmw[t] = ln_m_w[t]; s_lnmb[t] = ln_m_b[t];
    s_lnsw[t] = ln_s_w[t]; s_lnsb[t] = ln_s_b[t];
  }
  for (int i = t; i < 256; i += 256) {
    int r = i >> 4, c = i & 15;
    s_wq[r*17+c] = wq[i];
  }
  __syncthreads();

  int bk = blockIdx.x*16 + (t >> 4);
  int s = t & 15;
  int laneBase = (t & 63) & ~15;   // 16-lane group lives inside one wave

  float inv = 1.f / Abuf[bk];
  float u[16], h[16];
  #pragma unroll
  for (int j = 0; j < 16; ++j) {
    u[j] = upd[bk*16+j] * inv;     // normalized updates
    h[j] = slots[bk*16+j];         // slots_prev
  }
  float hs = slots[bk*16+s];       // avoid dynamic reg-array index

  float gir = s_bih[s],  giz = s_bih[16+s], gin = s_bih[32+s];
  float ghr = s_bhh[s],  ghz = s_bhh[16+s], ghn = s_bhh[32+s];
  #pragma unroll
  for (int j = 0; j < 16; ++j) {
    gir = fmaf(u[j], s_wih[s*17+j], gir);
    giz = fmaf(u[j], s_wih[(16+s)*17+j], giz);
    gin = fmaf(u[j], s_wih[(32+s)*17+j], gin);
    ghr = fmaf(h[j], s_whh[s*17+j], ghr);
    ghz = fmaf(h[j], s_whh[(16+s)*17+j], ghz);
    ghn = fmaf(h[j], s_whh[(32+s)*17+j], ghn);
  }
  float rr = sigmoid_f(gir + ghr);
  float zz = sigmoid_f(giz + ghz);
  float nn = tanh_f(gin + rr*ghn);
  float hn = (1.f-zz)*nn + zz*hs;

  // LayerNorm(h) over the 16-lane group
  float ssum = hn;
  #pragma unroll
  for (int m = 1; m < 16; m <<= 1) ssum += __shfl_xor(ssum, m);
  float mu = ssum*(1.f/16.f);
  float dv = hn - mu;
  float vs = dv*dv;
  #pragma unroll
  for (int m = 1; m < 16; m <<= 1) vs += __shfl_xor(vs, m);
  float rstd = rsqrtf(vs*(1.f/16.f) + 1e-5f);
  float y = dv*rstd*s_lnmw[s] + s_lnmb[s];

  float yv[16];
  #pragma unroll
  for (int j = 0; j < 16; ++j) yv[j] = __shfl(y, laneBase + j);

  // MLP layer 1: thread s owns hidden units j = i*16+s (bank-friendly)
  float h1[8];
  #pragma unroll
  for (int i = 0; i < 8; ++i) {
    int jj = i*16 + s;
    float a = s_b1[jj];
    #pragma unroll
    for (int q = 0; q < 16; ++q) a = fmaf(yv[q], s_w1[jj*17+q], a);
    h1[i] = fmaxf(a, 0.f);
  }
  // MLP layer 2 via shuffles
  float o = s_b2[s];
  #pragma unroll
  for (int i = 0; i < 8; ++i) {
    #pragma unroll
    for (int sp = 0; sp < 16; ++sp) {
      float hv = __shfl(h1[i], laneBase + sp);
      o = fmaf(hv, s_w2[s*129 + i*16 + sp], o);
    }
  }
  float slot_new = hn + o;
  slots[bk*16+s] = slot_new;

  if (prep_next) {
    // q for next iteration: wq @ LN_s(slots_new)
    float ss = slot_new;
    #pragma unroll
    for (int m = 1; m < 16; m <<= 1) ss += __shfl_xor(ss, m);
    float mu2 = ss*(1.f/16.f);
    float d2 = slot_new - mu2;
    float v2 = d2*d2;
    #pragma unroll
    for (int m = 1; m < 16; m <<= 1) v2 += __shfl_xor(v2, m);
    float rstd2 = rsqrtf(v2*(1.f/16.f) + 1e-5f);
    float y2 = d2*rstd2*s_lnsw[s] + s_lnsb[s];
    float qv = 0.f;
    #pragma unroll
    for (int sp = 0; sp < 16; ++sp) qv = fmaf(__shfl(y2, laneBase+sp), s_wq[s*17+sp], qv);
    qbuf[bk*16+s] = qv;
    // zero accumulators for next iteration (reads above are same-wave lockstep)
    upd[bk*16+s] = 0.f;
    if (s == 0) Abuf[bk] = 0.f;
  }
}

// ---------------- K4: normalize attn rows by A[b,k] ----------------
__global__ __launch_bounds__(256) void k_scale(float* __restrict__ attn,
                                               const float* __restrict__ Abuf)
{
  int bk = blockIdx.x;
  float inv = 1.f / Abuf[bk];
  float4* p = (float4*)(attn + (size_t)bk*4096);
  #pragma unroll 4
  for (int i = threadIdx.x; i < 1024; i += 256) {
    float4 v = p[i];
    v.x *= inv; v.y *= inv; v.z *= inv; v.w *= inv;
    p[i] = v;
  }
}

extern "C" void kernel_launch(void* const* d_in, const int* in_sizes, int n_in,
                              void* d_out, int out_size, void* d_ws, size_t ws_size,
                              hipStream_t stream)
{
  const float* inputs     = (const float*)d_in[0];
  const float* init_slots = (const float*)d_in[1];
  const float* ln_in_w    = (const float*)d_in[2];
  const float* ln_in_b    = (const float*)d_in[3];
  const float* ln_s_w     = (const float*)d_in[4];
  const float* ln_s_b     = (const float*)d_in[5];
  const float* ln_m_w     = (const float*)d_in[6];
  const float* ln_m_b     = (const float*)d_in[7];
  const float* wq         = (const float*)d_in[8];
  const float* wk         = (const float*)d_in[9];
  const float* wv         = (const float*)d_in[10];
  const float* w_ih       = (const float*)d_in[11];
  const float* w_hh       = (const float*)d_in[12];
  const float* b_ih       = (const float*)d_in[13];
  const float* b_hh       = (const float*)d_in[14];
  const float* mlp_w1     = (const float*)d_in[15];
  const float* mlp_b1     = (const float*)d_in[16];
  const float* mlp_w2     = (const float*)d_in[17];
  const float* mlp_b2     = (const float*)d_in[18];

  // workspace layout (floats); total ~16.1 MiB
  float* ws    = (float*)d_ws;
  float* wprepT= ws;                 // 8192
  float* mt    = ws + 8192;          // 64 (m[32], t[32])
  float* qbuf  = ws + 8320;          // 4096
  float* upd   = ws + 12416;         // 4096
  float* Abuf  = ws + 16512;         // 256
  float* kproj = ws + 16768;         // 2097152
  float* vproj = kproj + 2097152;    // 2097152

  float* out   = (float*)d_out;
  float* slots = out;                // [32,8,16]
  float* attn  = out + 4096;         // [32,8,4096]

  k_prep<<<32, 256, 0, stream>>>(ln_in_w, ln_in_b, wk, wv, init_slots,
                                 ln_s_w, ln_s_b, wq,
                                 wprepT, mt, qbuf, upd, Abuf, slots);
  k_proj<<<2048, 256, 0, stream>>>(inputs, wprepT, mt, kproj, vproj);
  for (int it = 0; it < 3; ++it) {
    int last = (it == 2);
    k_attn<<<512, 256, 0, stream>>>(kproj, vproj, qbuf, upd, Abuf, attn, last);
    k_gru<<<16, 256, 0, stream>>>(upd, Abuf, slots, qbuf,
                                  w_ih, w_hh, b_ih, b_hh,
                                  mlp_w1, mlp_b1, mlp_w2, mlp_b2,
                                  ln_m_w, ln_m_b, ln_s_w, ln_s_b,
                                  wq, last ? 0 : 1);
  }
  k_scale<<<256, 256, 0, stream>>>(attn, Abuf);
}